// Round 12
// baseline (240.979 us; speedup 1.0000x reference)
//
#include <hip/hip_runtime.h>
#include <hip/hip_bf16.h>
#include <stdint.h>

#define NN 50000       // nodes
#define NE 800000      // edges
#define IN_F 128
#define H_F 256
#define M_PAD 50048    // 782 * 64

typedef unsigned int uint32;
typedef unsigned short u16;
typedef __attribute__((ext_vector_type(8))) short short8;
typedef __attribute__((ext_vector_type(4))) float floatx4;

__device__ __forceinline__ float bf16_to_f(uint32 bits16) {
    union { uint32 u; float f; } c; c.u = bits16 << 16; return c.f;
}
__device__ __forceinline__ uint32 f_to_bf16(float f) {
    union { float f; uint32 u; } c; c.f = f;
    uint32 u = c.u;
    u += 0x7FFFu + ((u >> 16) & 1u);   // round-to-nearest-even
    return u >> 16;
}

// single-instruction byte->float converts (v_cvt_f32_ubyte0..3)
__device__ __forceinline__ float cvtub0(uint32 x) {
#if __has_builtin(__builtin_amdgcn_cvt_f32_ubyte0)
    return __builtin_amdgcn_cvt_f32_ubyte0(x);
#else
    return (float)(x & 0xFFu);
#endif
}
__device__ __forceinline__ float cvtub1(uint32 x) {
#if __has_builtin(__builtin_amdgcn_cvt_f32_ubyte1)
    return __builtin_amdgcn_cvt_f32_ubyte1(x);
#else
    return (float)((x >> 8) & 0xFFu);
#endif
}
__device__ __forceinline__ float cvtub2(uint32 x) {
#if __has_builtin(__builtin_amdgcn_cvt_f32_ubyte2)
    return __builtin_amdgcn_cvt_f32_ubyte2(x);
#else
    return (float)((x >> 16) & 0xFFu);
#endif
}
__device__ __forceinline__ float cvtub3(uint32 x) {
#if __has_builtin(__builtin_amdgcn_cvt_f32_ubyte3)
    return __builtin_amdgcn_cvt_f32_ubyte3(x);
#else
    return (float)(x >> 24);
#endif
}

// async global->LDS, 16B per lane. LDS dest must be wave-uniform base (HW adds lane*16).
__device__ __forceinline__ void gload_lds16(const void* g, void* l) {
    __builtin_amdgcn_global_load_lds((__attribute__((address_space(1))) void*)g,
                                     (__attribute__((address_space(3))) void*)l,
                                     16, 0, 0);
}

// ---------------- fused prep ----------------
// ranges: [cast+quant1 NN*32][wtrans1 65536][wtrans2 131072][zero q8 rows/scales 26][count NE]
// cast+quant1: id covers 16B (4 floats) of in_feat; row = id/32, 32 consecutive lanes
// per row (PREP_A is 256-divisible -> whole waves; shfl_xor <=16 stays in half-wave).
#define PREP_A (NN * 32)
#define PREP_B (256 * 256)
#define PREP_C (256 * 512)
#define PREP_Z 26
#define PREP_TOTAL (PREP_A + PREP_B + PREP_C + PREP_Z + NE)

__global__ void prep_kernel(const float* __restrict__ in_feat, u16* __restrict__ inA,
                            uint32* __restrict__ inA8, float* __restrict__ sIn,
                            const float* __restrict__ Ws1, const float* __restrict__ Wn1,
                            u16* __restrict__ BT1,
                            const float* __restrict__ Ws2, const float* __restrict__ Wn2,
                            u16* __restrict__ BT2,
                            uint32* __restrict__ h8, float* __restrict__ sH,
                            const int* __restrict__ dst, int* __restrict__ counts,
                            int* __restrict__ rank) {
    int id = blockIdx.x * 256 + threadIdx.x;
    if (id < PREP_A) {
        float4 v = *((const float4*)in_feat + id);
        ushort4 o;
        o.x = (u16)f_to_bf16(v.x); o.y = (u16)f_to_bf16(v.y);
        o.z = (u16)f_to_bf16(v.z); o.w = (u16)f_to_bf16(v.w);
        *((ushort4*)inA + id) = o;
        // quant1: rowmax over 32-lane group
        float m = fmaxf(fmaxf(fabsf(v.x), fabsf(v.y)), fmaxf(fabsf(v.z), fabsf(v.w)));
#pragma unroll
        for (int d = 1; d < 32; d <<= 1) m = fmaxf(m, __shfl_xor(m, d));
        float rs = (m > 0.0f) ? 127.0f / m : 0.0f;
        int q0 = (int)rintf(v.x * rs) + 128, q1 = (int)rintf(v.y * rs) + 128;
        int q2 = (int)rintf(v.z * rs) + 128, q3 = (int)rintf(v.w * rs) + 128;
        inA8[id] = (uint32)(q0 & 0xFF) | ((uint32)(q1 & 0xFF) << 8) |
                   ((uint32)(q2 & 0xFF) << 16) | ((uint32)(q3 & 0xFF) << 24);
        if ((id & 31) == 0) sIn[id >> 5] = m * (1.0f / 127.0f);
        return;
    }
    id -= PREP_A;
    if (id < PREP_B) {              // BT1[n][k], Ktot=256, K1=128
        int n = id >> 8, k = id & 255;
        float v = (k < 128) ? Ws1[(size_t)k * H_F + n] : Wn1[(size_t)(k - 128) * H_F + n];
        BT1[(size_t)n * 256 + k] = (u16)f_to_bf16(v);
        return;
    }
    id -= PREP_B;
    if (id < PREP_C) {              // BT2[n][k], Ktot=512, K1=256
        int n = id >> 9, k = id & 511;
        float v = (k < 256) ? Ws2[(size_t)k * H_F + n] : Wn2[(size_t)(k - 256) * H_F + n];
        BT2[(size_t)n * 512 + k] = (u16)f_to_bf16(v);
        return;
    }
    id -= PREP_C;
    if (id < PREP_Z) {              // zero q8 zero-rows and their scales
        uint4 z = {0u, 0u, 0u, 0u};
        if (id < 8)       *((uint4*)(inA8 + (size_t)NN * 32) + id) = z;
        else if (id < 24) *((uint4*)(h8   + (size_t)NN * 64) + (id - 8)) = z;
        else if (id == 24) sIn[NN] = 0.0f;
        else               sH[NN] = 0.0f;
        return;
    }
    id -= PREP_Z;
    if (id < NE) rank[id] = atomicAdd(&counts[dst[id]], 1);
}

// ---------------- CSR build ----------------

__global__ void scan1_kernel(const int* __restrict__ counts, int* __restrict__ row_start,
                             int* __restrict__ partials, int n) {
    __shared__ int s[256];
    int t = threadIdx.x;
    int i = blockIdx.x * 256 + t;
    int x = (i < n) ? counts[i] : 0;
    s[t] = x;
    __syncthreads();
    for (int off = 1; off < 256; off <<= 1) {
        int y = (t >= off) ? s[t - off] : 0;
        __syncthreads();
        s[t] += y;
        __syncthreads();
    }
    if (i < n) row_start[i] = s[t] - x;            // block-local exclusive
    if (t == 255) partials[blockIdx.x] = s[255];   // block total
}

// folds old scan2: each block re-scans the block-total array itself (196 ints)
__global__ void scan3_kernel(int* __restrict__ row_start, const int* __restrict__ partials,
                             const int* __restrict__ counts,
                             float* __restrict__ deg_inv, int n, int nparts) {
    __shared__ int s[256];
    int t = threadIdx.x;
    int x = (t < nparts) ? partials[t] : 0;
    s[t] = x;
    __syncthreads();
    for (int off = 1; off < 256; off <<= 1) {
        int y = (t >= off) ? s[t - off] : 0;
        __syncthreads();
        s[t] += y;
        __syncthreads();
    }
    int boff = blockIdx.x ? s[blockIdx.x - 1] : 0;   // exclusive prefix of this block
    int i = blockIdx.x * 256 + t;
    if (i >= n) return;
    row_start[i] += boff;
    int c = counts[i];
    deg_inv[i] = 1.0f / (float)(c > 1 ? c : 1);
}

// atomic-free: position = row_start[dst] + precomputed rank
__global__ void scatter_kernel(const int* __restrict__ src, const int* __restrict__ dst,
                               const int* __restrict__ rank, const int* __restrict__ row_start,
                               int* __restrict__ csr_src) {
    int e = blockIdx.x * 256 + threadIdx.x;
    if (e < NE) {
        int d = dst[e];
        csr_src[row_start[d] + rank[e]] = src[e];
    }
}

// ---------------- per-row biased-uint8 quantization of h (layer2 input) -------------
__global__ __launch_bounds__(256)
void quant_kernel(const u16* __restrict__ in, uint32* __restrict__ q8,
                  float* __restrict__ qs, int nrows) {
    const int w = threadIdx.x >> 6, lane = threadIdx.x & 63;
    const int row = blockIdx.x * 4 + w;
    if (row >= nrows) return;
    uint2 x = *(const uint2*)(in + (size_t)row * H_F + lane * 4);
    float v0 = bf16_to_f(x.x & 0xFFFFu), v1 = bf16_to_f(x.x >> 16);
    float v2 = bf16_to_f(x.y & 0xFFFFu), v3 = bf16_to_f(x.y >> 16);
    float m = fmaxf(fmaxf(fabsf(v0), fabsf(v1)), fmaxf(fabsf(v2), fabsf(v3)));
#pragma unroll
    for (int d = 1; d < 64; d <<= 1) m = fmaxf(m, __shfl_xor(m, d));
    float rs = (m > 0.0f) ? 127.0f / m : 0.0f;
    if (lane == 0) qs[row] = m * (1.0f / 127.0f);
    int q0 = (int)rintf(v0 * rs) + 128, q1 = (int)rintf(v1 * rs) + 128;
    int q2 = (int)rintf(v2 * rs) + 128, q3 = (int)rintf(v3 * rs) + 128;
    q8[(size_t)row * 64 + lane] = (uint32)(q0 & 0xFF) | ((uint32)(q1 & 0xFF) << 8) |
                                  ((uint32)(q2 & 0xFF) << 16) | ((uint32)(q3 & 0xFF) << 24);
}

// ---------------- aggregation: int8 gather, one wave per node ----------------
// F int8 bytes per row. LPR lanes/row (16B each), EPW edges/issue, U=4 in flight
// (16 VGPR -> real 4-deep MLP). Unconditional loads; empty slots hit zero row NN (s=0).
// Unpack via v_cvt_f32_ubyte0..3 (2 VALU/elem). value = acc - 128*ssum (bias folds).
template<int F>
__global__ __launch_bounds__(256)
void agg8_kernel(const uint32* __restrict__ q8, const float* __restrict__ qs,
                 const int* __restrict__ csr_src, const int* __restrict__ row_start,
                 const int* __restrict__ counts, const float* __restrict__ deg_inv,
                 u16* __restrict__ outp) {
    constexpr int WPR = F / 4;             // u32 words per row: 32 or 64
    constexpr int LPR = F / 16;            // lanes per row: 8 or 16
    constexpr int EPW = 64 / LPR;          // edges per issue: 8 or 4
    constexpr int U   = 4;                 // loads in flight per lane
    constexpr int EPI = EPW * U;           // edges per batch: 32 or 16
    const int w = threadIdx.x >> 6, lane = threadIdx.x & 63;
    const int node = blockIdx.x * 4 + w;
    if (node >= NN) return;
    const int start = row_start[node];
    const int cnt   = counts[node];
    const float dinv = deg_inv[node];
    const int g  = lane / LPR;
    const int wo = (lane % LPR) * 4;       // u32 word offset within row (16B/lane)
    const uint32* ftw = q8 + wo;

    int clampe = cnt > 0 ? cnt - 1 : 0;
    int myidx = csr_src[start + (lane < clampe ? lane : clampe)];
    if (lane >= cnt) myidx = NN;           // zero row: qs[NN] = 0
    float s_all = qs[myidx];
    float ssum = s_all;                    // per-lane own-edge scale (0 for idle lanes)

    float acc[16] = {};
    const int nb = cnt < 64 ? cnt : 64;
    for (int j = 0; j < nb; j += EPI) {
        uint4 x_[U]; float s_[U];
#pragma unroll
        for (int u = 0; u < U; ++u) {
            int sl = j + u * EPW + g;      // <= 63 always
            int idx = __shfl(myidx, sl);
            s_[u] = __shfl(s_all, sl);
            x_[u] = *(const uint4*)(ftw + (size_t)idx * WPR);
        }
#pragma unroll
        for (int u = 0; u < U; ++u) {
            const uint32 ww[4] = {x_[u].x, x_[u].y, x_[u].z, x_[u].w};
#pragma unroll
            for (int t = 0; t < 4; ++t) {
                acc[t * 4 + 0] += s_[u] * cvtub0(ww[t]);
                acc[t * 4 + 1] += s_[u] * cvtub1(ww[t]);
                acc[t * 4 + 2] += s_[u] * cvtub2(ww[t]);
                acc[t * 4 + 3] += s_[u] * cvtub3(ww[t]);
            }
        }
    }
    // rare tail: degree > 64 (count scale once per edge)
    for (int j = 64; j < cnt; j += EPW) {
        int e = j + g;
        int idx = (e < cnt) ? csr_src[start + e] : NN;
        uint4 x = *(const uint4*)(ftw + (size_t)idx * WPR);
        float s = qs[idx];
        if ((lane & (LPR - 1)) == 0) ssum += s;
        const uint32 ww[4] = {x.x, x.y, x.z, x.w};
#pragma unroll
        for (int t = 0; t < 4; ++t) {
            acc[t * 4 + 0] += s * cvtub0(ww[t]);
            acc[t * 4 + 1] += s * cvtub1(ww[t]);
            acc[t * 4 + 2] += s * cvtub2(ww[t]);
            acc[t * 4 + 3] += s * cvtub3(ww[t]);
        }
    }
#pragma unroll
    for (int d = 1; d < 64; d <<= 1) ssum += __shfl_xor(ssum, d);
#pragma unroll
    for (int d = LPR; d < 64; d <<= 1) {
#pragma unroll
        for (int k = 0; k < 16; ++k) acc[k] += __shfl_xor(acc[k], d);
    }
    if (g == 0) {
        const float bias = 128.0f * ssum;
        uint4 o0, o1;
        o0.x = f_to_bf16((acc[0]  - bias) * dinv) | (f_to_bf16((acc[1]  - bias) * dinv) << 16);
        o0.y = f_to_bf16((acc[2]  - bias) * dinv) | (f_to_bf16((acc[3]  - bias) * dinv) << 16);
        o0.z = f_to_bf16((acc[4]  - bias) * dinv) | (f_to_bf16((acc[5]  - bias) * dinv) << 16);
        o0.w = f_to_bf16((acc[6]  - bias) * dinv) | (f_to_bf16((acc[7]  - bias) * dinv) << 16);
        o1.x = f_to_bf16((acc[8]  - bias) * dinv) | (f_to_bf16((acc[9]  - bias) * dinv) << 16);
        o1.y = f_to_bf16((acc[10] - bias) * dinv) | (f_to_bf16((acc[11] - bias) * dinv) << 16);
        o1.z = f_to_bf16((acc[12] - bias) * dinv) | (f_to_bf16((acc[13] - bias) * dinv) << 16);
        o1.w = f_to_bf16((acc[14] - bias) * dinv) | (f_to_bf16((acc[15] - bias) * dinv) << 16);
        uint32* op = (uint32*)outp + (size_t)node * (F / 2) + wo * 2;
        *(uint4*)op = o0;
        *(uint4*)(op + 4) = o1;
    }
}

// ---------------- fused GEMM: C = A1*B1 + A2*B2 + bias (+relu->bf16) ----------------
// A1,A2: [M_PAD][K1] bf16 row-major. BT: [256][2*K1] bf16 (transposed, stacked).
// 64 x 256 tile (full N per block -> A staged ONCE; B L2-resident). 782 blocks.
// BK=64, 4 waves side-by-side in N. LDS XOR-swizzled (rule #21 on the source).
template<int RELU_BF16>
__global__ __launch_bounds__(256)
void gemm_kernel(const u16* __restrict__ A1, const u16* __restrict__ A2, int K1,
                 const u16* __restrict__ BT, const float* __restrict__ bias,
                 void* __restrict__ outp, int M) {
    __shared__ char lds[40960];   // A: [0,8192), B: [8192,40960)
    const int tid = threadIdx.x;
    const int w = tid >> 6, lane = tid & 63;
    const int brow = blockIdx.x * 64;
    const int Ktot = 2 * K1;
    const int NT = Ktot >> 6;   // K-tiles of 64
    const int T1 = K1 >> 6;     // tiles from A1
    const int l15 = lane & 15, l7 = lane & 7, kg = lane >> 4;
    const int srow = w * 8 + (lane >> 3);   // staging row within 32-row issue group
    const int scb = (lane & 7) * 16;        // staging byte-col slot
    const size_t sA = (size_t)K1 * 2;       // bytes per A row
    const size_t sB = (size_t)Ktot * 2;     // bytes per BT row

    floatx4 acc[4][4] = {};

    for (int kt = 0; kt < NT; ++kt) {
        const char* Ab; int ka;
        if (kt < T1) { Ab = (const char*)A1; ka = kt * 64; }
        else         { Ab = (const char*)A2; ka = (kt - T1) * 64; }
#pragma unroll
        for (int i = 0; i < 2; ++i) {       // A: 64 rows
            int row = i * 32 + srow;
            const char* g = Ab + (size_t)(brow + row) * sA + ka * 2 + (scb ^ ((row & 7) << 4));
            gload_lds16(g, &lds[i * 4096 + w * 1024]);
        }
#pragma unroll
        for (int i = 0; i < 8; ++i) {       // B: all 256 BT rows
            int row = i * 32 + srow;
            const char* g = (const char*)BT + (size_t)row * sB + kt * 128 + (scb ^ ((row & 7) << 4));
            gload_lds16(g, &lds[8192 + i * 4096 + w * 1024]);
        }
        __syncthreads();
#pragma unroll
        for (int kk = 0; kk < 2; ++kk) {
            short8 a[4], b[4];
            const int cbyte = (kk * 64 + kg * 16) ^ (l7 << 4);
#pragma unroll
            for (int m = 0; m < 4; ++m)
                a[m] = *(const short8*)&lds[(m * 16 + l15) * 128 + cbyte];
#pragma unroll
            for (int n = 0; n < 4; ++n)
                b[n] = *(const short8*)&lds[8192 + (w * 64 + n * 16 + l15) * 128 + cbyte];
#pragma unroll
            for (int m = 0; m < 4; ++m)
#pragma unroll
                for (int n = 0; n < 4; ++n)
                    acc[m][n] = __builtin_amdgcn_mfma_f32_16x16x32_bf16(a[m], b[n], acc[m][n], 0, 0, 0);
        }
        __syncthreads();
    }

    const int ocol0 = w * 64;
#pragma unroll
    for (int m = 0; m < 4; ++m) {
#pragma unroll
        for (int j = 0; j < 4; ++j) {
            int row = brow + m * 16 + kg * 4 + j;
            if (row < M) {
#pragma unroll
                for (int n = 0; n < 4; ++n) {
                    int col = ocol0 + n * 16 + l15;
                    float v = acc[m][n][j] + bias[col];
                    if (RELU_BF16) {
                        v = fmaxf(v, 0.0f);
                        ((u16*)outp)[(size_t)row * H_F + col] = (u16)f_to_bf16(v);
                    } else {
                        ((float*)outp)[(size_t)row * H_F + col] = v;
                    }
                }
            }
        }
    }
}

// ---------------- launch ----------------

extern "C" void kernel_launch(void* const* d_in, const int* in_sizes, int n_in,
                              void* d_out, int out_size, void* d_ws, size_t ws_size,
                              hipStream_t stream) {
    const float* in_feat  = (const float*)d_in[0];
    const int*   src      = (const int*)d_in[1];
    const int*   dst      = (const int*)d_in[2];
    const float* W_self1  = (const float*)d_in[3];
    const float* W_neigh1 = (const float*)d_in[4];
    const float* b1       = (const float*)d_in[5];
    const float* W_self2  = (const float*)d_in[6];
    const float* W_neigh2 = (const float*)d_in[7];
    const float* b2       = (const float*)d_in[8];
    float* out = (float*)d_out;

    char* p = (char*)d_ws;
    auto alloc = [&](size_t bytes) { char* r = p; p += (bytes + 255) & ~(size_t)255; return r; };
    int*    counts    = (int*)alloc((size_t)NN * 4);
    int*    row_start = (int*)alloc((size_t)NN * 4);
    int*    partials  = (int*)alloc(256 * 4);
    float*  deg_inv   = (float*)alloc((size_t)NN * 4);
    int*    rank      = (int*)alloc((size_t)NE * 4);
    int*    csr_src   = (int*)alloc((size_t)NE * 4 + 256);
    u16*    inA       = (u16*)alloc((size_t)M_PAD * IN_F * 2);
    u16*    hn1       = (u16*)alloc((size_t)M_PAD * IN_F * 2);
    u16*    h         = (u16*)alloc((size_t)M_PAD * H_F * 2);
    u16*    hn2       = (u16*)alloc((size_t)M_PAD * H_F * 2);
    u16*    BT1       = (u16*)alloc((size_t)256 * 256 * 2);
    u16*    BT2       = (u16*)alloc((size_t)256 * 512 * 2);
    uint32* inA8      = (uint32*)alloc((size_t)(NN + 1) * IN_F);
    float*  sIn       = (float*)alloc((size_t)(NN + 1) * 4);
    uint32* h8        = (uint32*)alloc((size_t)(NN + 1) * H_F);
    float*  sH        = (float*)alloc((size_t)(NN + 1) * 4);

    hipMemsetAsync(counts, 0, (size_t)NN * 4, stream);

    prep_kernel<<<(PREP_TOTAL + 255) / 256, 256, 0, stream>>>(
        in_feat, inA, inA8, sIn, W_self1, W_neigh1, BT1, W_self2, W_neigh2, BT2,
        h8, sH, dst, counts, rank);

    const int SB = (NN + 255) / 256;   // 196
    scan1_kernel<<<SB, 256, 0, stream>>>(counts, row_start, partials, NN);
    scan3_kernel<<<SB, 256, 0, stream>>>(row_start, partials, counts, deg_inv, NN, SB);
    scatter_kernel<<<(NE + 255) / 256, 256, 0, stream>>>(src, dst, rank, row_start, csr_src);

    // layer 1
    agg8_kernel<IN_F><<<(NN + 3) / 4, 256, 0, stream>>>(inA8, sIn, csr_src, row_start, counts, deg_inv, hn1);
    gemm_kernel<1><<<M_PAD / 64, 256, 0, stream>>>(inA, hn1, 128, BT1, b1, (void*)h, NN);
    // layer 2
    quant_kernel<<<(NN + 3) / 4, 256, 0, stream>>>(h, h8, sH, NN);
    agg8_kernel<H_F><<<(NN + 3) / 4, 256, 0, stream>>>(h8, sH, csr_src, row_start, counts, deg_inv, hn2);
    gemm_kernel<0><<<M_PAD / 64, 256, 0, stream>>>(h, hn2, 256, BT2, b2, (void*)out, NN);
}

// Round 13
// 210.943 us; speedup vs baseline: 1.1424x; 1.1424x over previous
//
#include <hip/hip_runtime.h>
#include <hip/hip_bf16.h>
#include <stdint.h>

#define NN 50000       // nodes
#define NE 800000      // edges
#define IN_F 128
#define H_F 256
#define M_PAD 50048    // 782 * 64

typedef unsigned int uint32;
typedef unsigned short u16;
typedef __attribute__((ext_vector_type(8))) short short8;
typedef __attribute__((ext_vector_type(4))) float floatx4;

__device__ __forceinline__ float bf16_to_f(uint32 bits16) {
    union { uint32 u; float f; } c; c.u = bits16 << 16; return c.f;
}
__device__ __forceinline__ uint32 f_to_bf16(float f) {
    union { float f; uint32 u; } c; c.f = f;
    uint32 u = c.u;
    u += 0x7FFFu + ((u >> 16) & 1u);   // round-to-nearest-even
    return u >> 16;
}

// async global->LDS, 16B per lane. LDS dest must be wave-uniform base (HW adds lane*16).
__device__ __forceinline__ void gload_lds16(const void* g, void* l) {
    __builtin_amdgcn_global_load_lds((__attribute__((address_space(1))) void*)g,
                                     (__attribute__((address_space(3))) void*)l,
                                     16, 0, 0);
}

// ---------------- fused prep: cast feats + transpose/stack weights + zero-rows
//                  + degree count WITH per-edge rank (atomic return stored coalesced)
#define PREP_A (NN * IN_F / 4)
#define PREP_B (256 * 256)
#define PREP_C (256 * 512)
#define PREP_Z (16 + 32)            // 16B-granule zero stores: 256B (inA) + 512B (h)
#define PREP_TOTAL (PREP_A + PREP_B + PREP_C + PREP_Z + NE)

__global__ void prep_kernel(const float* __restrict__ in_feat, u16* __restrict__ inA,
                            const float* __restrict__ Ws1, const float* __restrict__ Wn1,
                            u16* __restrict__ BT1,
                            const float* __restrict__ Ws2, const float* __restrict__ Wn2,
                            u16* __restrict__ BT2,
                            u16* __restrict__ h,
                            const int* __restrict__ dst, int* __restrict__ counts,
                            int* __restrict__ rank) {
    int id = blockIdx.x * 256 + threadIdx.x;
    if (id < PREP_A) {
        float4 v = *((const float4*)in_feat + id);
        ushort4 o;
        o.x = (u16)f_to_bf16(v.x); o.y = (u16)f_to_bf16(v.y);
        o.z = (u16)f_to_bf16(v.z); o.w = (u16)f_to_bf16(v.w);
        *((ushort4*)inA + id) = o;
        return;
    }
    id -= PREP_A;
    if (id < PREP_B) {              // BT1[n][k], Ktot=256, K1=128
        int n = id >> 8, k = id & 255;
        float v = (k < 128) ? Ws1[(size_t)k * H_F + n] : Wn1[(size_t)(k - 128) * H_F + n];
        BT1[(size_t)n * 256 + k] = (u16)f_to_bf16(v);
        return;
    }
    id -= PREP_B;
    if (id < PREP_C) {              // BT2[n][k], Ktot=512, K1=256
        int n = id >> 9, k = id & 511;
        float v = (k < 256) ? Ws2[(size_t)k * H_F + n] : Wn2[(size_t)(k - 256) * H_F + n];
        BT2[(size_t)n * 512 + k] = (u16)f_to_bf16(v);
        return;
    }
    id -= PREP_C;
    if (id < PREP_Z) {              // zero row NN of inA (256B) and h (512B)
        uint4 z = {0u, 0u, 0u, 0u};
        if (id < 16) *((uint4*)(inA + (size_t)NN * IN_F) + id) = z;
        else         *((uint4*)(h   + (size_t)NN * H_F)  + (id - 16)) = z;
        return;
    }
    id -= PREP_Z;
    if (id < NE) rank[id] = atomicAdd(&counts[dst[id]], 1);
}

// ---------------- CSR build ----------------

__global__ void scan1_kernel(const int* __restrict__ counts, int* __restrict__ row_start,
                             int* __restrict__ partials, int n) {
    __shared__ int s[256];
    int t = threadIdx.x;
    int i = blockIdx.x * 256 + t;
    int x = (i < n) ? counts[i] : 0;
    s[t] = x;
    __syncthreads();
    for (int off = 1; off < 256; off <<= 1) {
        int y = (t >= off) ? s[t - off] : 0;
        __syncthreads();
        s[t] += y;
        __syncthreads();
    }
    if (i < n) row_start[i] = s[t] - x;            // block-local exclusive
    if (t == 255) partials[blockIdx.x] = s[255];   // block total
}

// folds old scan2: each block re-scans the block-total array itself (196 ints)
__global__ void scan3_kernel(int* __restrict__ row_start, const int* __restrict__ partials,
                             const int* __restrict__ counts,
                             float* __restrict__ deg_inv, int n, int nparts) {
    __shared__ int s[256];
    int t = threadIdx.x;
    int x = (t < nparts) ? partials[t] : 0;
    s[t] = x;
    __syncthreads();
    for (int off = 1; off < 256; off <<= 1) {
        int y = (t >= off) ? s[t - off] : 0;
        __syncthreads();
        s[t] += y;
        __syncthreads();
    }
    int boff = blockIdx.x ? s[blockIdx.x - 1] : 0;   // exclusive prefix of this block
    int i = blockIdx.x * 256 + t;
    if (i >= n) return;
    row_start[i] += boff;
    int c = counts[i];
    deg_inv[i] = 1.0f / (float)(c > 1 ? c : 1);
}

// atomic-free: position = row_start[dst] + precomputed rank
__global__ void scatter_kernel(const int* __restrict__ src, const int* __restrict__ dst,
                               const int* __restrict__ rank, const int* __restrict__ row_start,
                               int* __restrict__ csr_src) {
    int e = blockIdx.x * 256 + threadIdx.x;
    if (e < NE) {
        int d = dst[e];
        csr_src[row_start[d] + rank[e]] = src[e];
    }
}

// ---------------- aggregation: one wave per node (R4 best-measured shape) ----------
// DW = u32 words per feature row (64 -> D=128, 128 -> D=256).
// Edge indices loaded ONCE (one per lane, deg<=64 covers ~all); inactive lanes ->
// pre-zeroed row NN. Broadcast via __shfl, U unconditional dwordx4 loads in flight.
template<int DW>
__global__ __launch_bounds__(256)
void agg_kernel(const u16* __restrict__ feats, const int* __restrict__ csr_src,
                const int* __restrict__ row_start, const int* __restrict__ counts,
                const float* __restrict__ deg_inv, u16* __restrict__ outp) {
    constexpr int LPR = DW / 4;            // lanes per row (16B each): 16 or 32
    constexpr int EPW = 64 / LPR;          // edges per batch-slot: 4 or 2
    constexpr int U   = (DW == 64) ? 8 : 16;
    constexpr int EPI = EPW * U;           // 32 edges per batch
    const int w = threadIdx.x >> 6, lane = threadIdx.x & 63;
    const int node = blockIdx.x * 4 + w;
    if (node >= NN) return;
    const int start = row_start[node];
    const int cnt   = counts[node];
    const float dinv = deg_inv[node];
    const int g  = lane / LPR;
    const int wo = (lane % LPR) * 4;       // word offset within row
    const uint32* ftw = (const uint32*)feats + wo;

    // load up to 64 edge indices, one per lane; inactive lanes -> zero row NN
    int clampe = cnt > 0 ? cnt - 1 : 0;
    int myidx = csr_src[start + (lane < clampe ? lane : clampe)];
    if (lane >= cnt) myidx = NN;

    float acc[8] = {};
    const int nb = cnt < 64 ? cnt : 64;
    for (int j = 0; j < nb; j += EPI) {
        uint4 x_[U];
#pragma unroll
        for (int u = 0; u < U; ++u) {
            int idx = __shfl(myidx, j + u * EPW + g);   // <= 63 always
            x_[u] = *(const uint4*)(ftw + (size_t)idx * DW);
        }
#pragma unroll
        for (int u = 0; u < U; ++u) {
            acc[0] += bf16_to_f(x_[u].x & 0xFFFFu); acc[1] += bf16_to_f(x_[u].x >> 16);
            acc[2] += bf16_to_f(x_[u].y & 0xFFFFu); acc[3] += bf16_to_f(x_[u].y >> 16);
            acc[4] += bf16_to_f(x_[u].z & 0xFFFFu); acc[5] += bf16_to_f(x_[u].z >> 16);
            acc[6] += bf16_to_f(x_[u].w & 0xFFFFu); acc[7] += bf16_to_f(x_[u].w >> 16);
        }
    }
    // rare tail: degree > 64
    for (int j = 64; j < cnt; j += EPW) {
        int e = j + g;
        int idx = (e < cnt) ? csr_src[start + e] : NN;
        uint4 x = *(const uint4*)(ftw + (size_t)idx * DW);
        acc[0] += bf16_to_f(x.x & 0xFFFFu); acc[1] += bf16_to_f(x.x >> 16);
        acc[2] += bf16_to_f(x.y & 0xFFFFu); acc[3] += bf16_to_f(x.y >> 16);
        acc[4] += bf16_to_f(x.z & 0xFFFFu); acc[5] += bf16_to_f(x.z >> 16);
        acc[6] += bf16_to_f(x.w & 0xFFFFu); acc[7] += bf16_to_f(x.w >> 16);
    }
#pragma unroll
    for (int k = 0; k < 8; ++k) {
        if (LPR <= 16) acc[k] += __shfl_xor(acc[k], 16);
        acc[k] += __shfl_xor(acc[k], 32);
    }
    if (g == 0) {
        uint4 o;
        o.x = f_to_bf16(acc[0] * dinv) | (f_to_bf16(acc[1] * dinv) << 16);
        o.y = f_to_bf16(acc[2] * dinv) | (f_to_bf16(acc[3] * dinv) << 16);
        o.z = f_to_bf16(acc[4] * dinv) | (f_to_bf16(acc[5] * dinv) << 16);
        o.w = f_to_bf16(acc[6] * dinv) | (f_to_bf16(acc[7] * dinv) << 16);
        *(uint4*)((uint32*)outp + (size_t)node * DW + wo) = o;
    }
}

// ---------------- fused GEMM: C = A1*B1 + A2*B2 + bias (+relu->bf16) ----------------
// A1,A2: [M_PAD][K1] bf16 row-major. BT: [256][2*K1] bf16 (transposed, stacked).
// 64 x 256 tile (full N per block -> A staged ONCE; B L2-resident). 782 blocks.
// BK=64, 4 waves side-by-side in N. LDS XOR-swizzled (rule #21 on the source).
template<int RELU_BF16>
__global__ __launch_bounds__(256)
void gemm_kernel(const u16* __restrict__ A1, const u16* __restrict__ A2, int K1,
                 const u16* __restrict__ BT, const float* __restrict__ bias,
                 void* __restrict__ outp, int M) {
    __shared__ char lds[40960];   // A: [0,8192), B: [8192,40960)
    const int tid = threadIdx.x;
    const int w = tid >> 6, lane = tid & 63;
    const int brow = blockIdx.x * 64;
    const int Ktot = 2 * K1;
    const int NT = Ktot >> 6;   // K-tiles of 64
    const int T1 = K1 >> 6;     // tiles from A1
    const int l15 = lane & 15, l7 = lane & 7, kg = lane >> 4;
    const int srow = w * 8 + (lane >> 3);   // staging row within 32-row issue group
    const int scb = (lane & 7) * 16;        // staging byte-col slot
    const size_t sA = (size_t)K1 * 2;       // bytes per A row
    const size_t sB = (size_t)Ktot * 2;     // bytes per BT row

    floatx4 acc[4][4] = {};

    for (int kt = 0; kt < NT; ++kt) {
        const char* Ab; int ka;
        if (kt < T1) { Ab = (const char*)A1; ka = kt * 64; }
        else         { Ab = (const char*)A2; ka = (kt - T1) * 64; }
#pragma unroll
        for (int i = 0; i < 2; ++i) {       // A: 64 rows
            int row = i * 32 + srow;
            const char* g = Ab + (size_t)(brow + row) * sA + ka * 2 + (scb ^ ((row & 7) << 4));
            gload_lds16(g, &lds[i * 4096 + w * 1024]);
        }
#pragma unroll
        for (int i = 0; i < 8; ++i) {       // B: all 256 BT rows
            int row = i * 32 + srow;
            const char* g = (const char*)BT + (size_t)row * sB + kt * 128 + (scb ^ ((row & 7) << 4));
            gload_lds16(g, &lds[8192 + i * 4096 + w * 1024]);
        }
        __syncthreads();
#pragma unroll
        for (int kk = 0; kk < 2; ++kk) {
            short8 a[4], b[4];
            const int cbyte = (kk * 64 + kg * 16) ^ (l7 << 4);
#pragma unroll
            for (int m = 0; m < 4; ++m)
                a[m] = *(const short8*)&lds[(m * 16 + l15) * 128 + cbyte];
#pragma unroll
            for (int n = 0; n < 4; ++n)
                b[n] = *(const short8*)&lds[8192 + (w * 64 + n * 16 + l15) * 128 + cbyte];
#pragma unroll
            for (int m = 0; m < 4; ++m)
#pragma unroll
                for (int n = 0; n < 4; ++n)
                    acc[m][n] = __builtin_amdgcn_mfma_f32_16x16x32_bf16(a[m], b[n], acc[m][n], 0, 0, 0);
        }
        __syncthreads();
    }

    const int ocol0 = w * 64;
#pragma unroll
    for (int m = 0; m < 4; ++m) {
#pragma unroll
        for (int j = 0; j < 4; ++j) {
            int row = brow + m * 16 + kg * 4 + j;
            if (row < M) {
#pragma unroll
                for (int n = 0; n < 4; ++n) {
                    int col = ocol0 + n * 16 + l15;
                    float v = acc[m][n][j] + bias[col];
                    if (RELU_BF16) {
                        v = fmaxf(v, 0.0f);
                        ((u16*)outp)[(size_t)row * H_F + col] = (u16)f_to_bf16(v);
                    } else {
                        ((float*)outp)[(size_t)row * H_F + col] = v;
                    }
                }
            }
        }
    }
}

// ---------------- launch ----------------

extern "C" void kernel_launch(void* const* d_in, const int* in_sizes, int n_in,
                              void* d_out, int out_size, void* d_ws, size_t ws_size,
                              hipStream_t stream) {
    const float* in_feat  = (const float*)d_in[0];
    const int*   src      = (const int*)d_in[1];
    const int*   dst      = (const int*)d_in[2];
    const float* W_self1  = (const float*)d_in[3];
    const float* W_neigh1 = (const float*)d_in[4];
    const float* b1       = (const float*)d_in[5];
    const float* W_self2  = (const float*)d_in[6];
    const float* W_neigh2 = (const float*)d_in[7];
    const float* b2       = (const float*)d_in[8];
    float* out = (float*)d_out;

    char* p = (char*)d_ws;
    auto alloc = [&](size_t bytes) { char* r = p; p += (bytes + 255) & ~(size_t)255; return r; };
    int*   counts    = (int*)alloc((size_t)NN * 4);
    int*   row_start = (int*)alloc((size_t)NN * 4);
    int*   partials  = (int*)alloc(256 * 4);
    float* deg_inv   = (float*)alloc((size_t)NN * 4);
    int*   rank      = (int*)alloc((size_t)NE * 4);
    int*   csr_src   = (int*)alloc((size_t)NE * 4 + 256);
    u16*   inA       = (u16*)alloc((size_t)M_PAD * IN_F * 2);
    u16*   hn1       = (u16*)alloc((size_t)M_PAD * IN_F * 2);
    u16*   h         = (u16*)alloc((size_t)M_PAD * H_F * 2);
    u16*   hn2       = (u16*)alloc((size_t)M_PAD * H_F * 2);
    u16*   BT1       = (u16*)alloc((size_t)256 * 256 * 2);
    u16*   BT2       = (u16*)alloc((size_t)256 * 512 * 2);

    hipMemsetAsync(counts, 0, (size_t)NN * 4, stream);

    prep_kernel<<<(PREP_TOTAL + 255) / 256, 256, 0, stream>>>(
        in_feat, inA, W_self1, W_neigh1, BT1, W_self2, W_neigh2, BT2, h, dst, counts, rank);

    const int SB = (NN + 255) / 256;   // 196
    scan1_kernel<<<SB, 256, 0, stream>>>(counts, row_start, partials, NN);
    scan3_kernel<<<SB, 256, 0, stream>>>(row_start, partials, counts, deg_inv, NN, SB);
    scatter_kernel<<<(NE + 255) / 256, 256, 0, stream>>>(src, dst, rank, row_start, csr_src);

    // layer 1
    agg_kernel<IN_F / 2><<<(NN + 3) / 4, 256, 0, stream>>>(inA, csr_src, row_start, counts, deg_inv, hn1);
    gemm_kernel<1><<<M_PAD / 64, 256, 0, stream>>>(inA, hn1, 128, BT1, b1, (void*)h, NN);
    // layer 2
    agg_kernel<H_F / 2><<<(NN + 3) / 4, 256, 0, stream>>>(h, csr_src, row_start, counts, deg_inv, hn2);
    gemm_kernel<0><<<M_PAD / 64, 256, 0, stream>>>(h, hn2, 256, BT2, b2, (void*)out, NN);
}

// Round 14
// 209.817 us; speedup vs baseline: 1.1485x; 1.0054x over previous
//
#include <hip/hip_runtime.h>
#include <hip/hip_bf16.h>
#include <stdint.h>

#define NN 50000       // nodes
#define NE 800000      // edges
#define IN_F 128
#define H_F 256
#define M_PAD 50048    // 782 * 64

typedef unsigned int uint32;
typedef unsigned short u16;
typedef __attribute__((ext_vector_type(8))) short short8;
typedef __attribute__((ext_vector_type(4))) float floatx4;

__device__ __forceinline__ float bf16_to_f(uint32 bits16) {
    union { uint32 u; float f; } c; c.u = bits16 << 16; return c.f;
}
__device__ __forceinline__ uint32 f_to_bf16(float f) {
    union { float f; uint32 u; } c; c.f = f;
    uint32 u = c.u;
    u += 0x7FFFu + ((u >> 16) & 1u);   // round-to-nearest-even
    return u >> 16;
}

// async global->LDS, 16B per lane. LDS dest must be wave-uniform base (HW adds lane*16).
__device__ __forceinline__ void gload_lds16(const void* g, void* l) {
    __builtin_amdgcn_global_load_lds((__attribute__((address_space(1))) void*)g,
                                     (__attribute__((address_space(3))) void*)l,
                                     16, 0, 0);
}

// ---------------- fused prep: cast feats + transpose/stack weights + zero-rows
//   + degree count into 4 REPLICA counters, 4 edges/thread (4 independent atomics
//   in flight per lane -> 4x latency hiding; replicas kill intra-thread and 4x
//   cross-thread same-line contention). rank[e] is local to replica e&3.
#define PREP_A (NN * IN_F / 4)
#define PREP_B (256 * 256)
#define PREP_C (256 * 512)
#define PREP_Z (16 + 32)            // 16B-granule zero stores: 256B (inA) + 512B (h)
#define PREP_E (NE / 4)             // 4 edges per thread
#define PREP_TOTAL (PREP_A + PREP_B + PREP_C + PREP_Z + PREP_E)

__global__ void prep_kernel(const float* __restrict__ in_feat, u16* __restrict__ inA,
                            const float* __restrict__ Ws1, const float* __restrict__ Wn1,
                            u16* __restrict__ BT1,
                            const float* __restrict__ Ws2, const float* __restrict__ Wn2,
                            u16* __restrict__ BT2,
                            u16* __restrict__ h,
                            const int* __restrict__ dst, int* __restrict__ counts4,
                            int* __restrict__ rank) {
    int id = blockIdx.x * 256 + threadIdx.x;
    if (id < PREP_A) {
        float4 v = *((const float4*)in_feat + id);
        ushort4 o;
        o.x = (u16)f_to_bf16(v.x); o.y = (u16)f_to_bf16(v.y);
        o.z = (u16)f_to_bf16(v.z); o.w = (u16)f_to_bf16(v.w);
        *((ushort4*)inA + id) = o;
        return;
    }
    id -= PREP_A;
    if (id < PREP_B) {              // BT1[n][k], Ktot=256, K1=128
        int n = id >> 8, k = id & 255;
        float v = (k < 128) ? Ws1[(size_t)k * H_F + n] : Wn1[(size_t)(k - 128) * H_F + n];
        BT1[(size_t)n * 256 + k] = (u16)f_to_bf16(v);
        return;
    }
    id -= PREP_B;
    if (id < PREP_C) {              // BT2[n][k], Ktot=512, K1=256
        int n = id >> 9, k = id & 511;
        float v = (k < 256) ? Ws2[(size_t)k * H_F + n] : Wn2[(size_t)(k - 256) * H_F + n];
        BT2[(size_t)n * 512 + k] = (u16)f_to_bf16(v);
        return;
    }
    id -= PREP_C;
    if (id < PREP_Z) {              // zero row NN of inA (256B) and h (512B)
        uint4 z = {0u, 0u, 0u, 0u};
        if (id < 16) *((uint4*)(inA + (size_t)NN * IN_F) + id) = z;
        else         *((uint4*)(h   + (size_t)NN * H_F)  + (id - 16)) = z;
        return;
    }
    id -= PREP_Z;
    if (id < PREP_E) {              // 4 edges: replicas 0..3 -> independent atomics
        int4 d = *((const int4*)dst + id);
        int4 r;
        r.x = atomicAdd(&counts4[0 * NN + d.x], 1);
        r.y = atomicAdd(&counts4[1 * NN + d.y], 1);
        r.z = atomicAdd(&counts4[2 * NN + d.z], 1);
        r.w = atomicAdd(&counts4[3 * NN + d.w], 1);
        *((int4*)rank + id) = r;
    }
}

// ---------------- CSR build ----------------

__global__ void scan1_kernel(const int* __restrict__ counts4, int* __restrict__ row_start,
                             int* __restrict__ partials, int n) {
    __shared__ int s[256];
    int t = threadIdx.x;
    int i = blockIdx.x * 256 + t;
    int x = 0;
    if (i < n)
        x = counts4[i] + counts4[NN + i] + counts4[2 * NN + i] + counts4[3 * NN + i];
    s[t] = x;
    __syncthreads();
    for (int off = 1; off < 256; off <<= 1) {
        int y = (t >= off) ? s[t - off] : 0;
        __syncthreads();
        s[t] += y;
        __syncthreads();
    }
    if (i < n) row_start[i] = s[t] - x;            // block-local exclusive
    if (t == 255) partials[blockIdx.x] = s[255];   // block total
}

// folds old scan2 + emits per-replica bases, total counts, deg_inv
__global__ void scan3_kernel(int* __restrict__ row_start, const int* __restrict__ partials,
                             const int* __restrict__ counts4, int* __restrict__ base4,
                             int* __restrict__ counts_tot,
                             float* __restrict__ deg_inv, int n, int nparts) {
    __shared__ int s[256];
    int t = threadIdx.x;
    int x = (t < nparts) ? partials[t] : 0;
    s[t] = x;
    __syncthreads();
    for (int off = 1; off < 256; off <<= 1) {
        int y = (t >= off) ? s[t - off] : 0;
        __syncthreads();
        s[t] += y;
        __syncthreads();
    }
    int boff = blockIdx.x ? s[blockIdx.x - 1] : 0;   // exclusive prefix of this block
    int i = blockIdx.x * 256 + t;
    if (i >= n) return;
    int rs = row_start[i] + boff;
    row_start[i] = rs;
    int c0 = counts4[i], c1 = counts4[NN + i], c2 = counts4[2 * NN + i], c3 = counts4[3 * NN + i];
    base4[i]          = rs;
    base4[NN + i]     = rs + c0;
    base4[2 * NN + i] = rs + c0 + c1;
    base4[3 * NN + i] = rs + c0 + c1 + c2;
    int c = c0 + c1 + c2 + c3;
    counts_tot[i] = c;
    deg_inv[i] = 1.0f / (float)(c > 1 ? c : 1);
}

// atomic-free: position = base4[replica][dst] + precomputed replica-local rank
__global__ void scatter_kernel(const int* __restrict__ src, const int* __restrict__ dst,
                               const int* __restrict__ rank, const int* __restrict__ base4,
                               int* __restrict__ csr_src) {
    int e = blockIdx.x * 256 + threadIdx.x;
    if (e < NE) {
        int d = dst[e];
        csr_src[base4[(e & 3) * NN + d] + rank[e]] = src[e];
    }
}

// ---------------- aggregation: one wave per node (R4 best-measured shape) ----------
// DW = u32 words per feature row (64 -> D=128, 128 -> D=256).
// Edge indices loaded ONCE (one per lane, deg<=64 covers ~all); inactive lanes ->
// pre-zeroed row NN. Broadcast via __shfl, U unconditional dwordx4 loads in flight.
template<int DW>
__global__ __launch_bounds__(256)
void agg_kernel(const u16* __restrict__ feats, const int* __restrict__ csr_src,
                const int* __restrict__ row_start, const int* __restrict__ counts,
                const float* __restrict__ deg_inv, u16* __restrict__ outp) {
    constexpr int LPR = DW / 4;            // lanes per row (16B each): 16 or 32
    constexpr int EPW = 64 / LPR;          // edges per batch-slot: 4 or 2
    constexpr int U   = (DW == 64) ? 8 : 16;
    constexpr int EPI = EPW * U;           // 32 edges per batch
    const int w = threadIdx.x >> 6, lane = threadIdx.x & 63;
    const int node = blockIdx.x * 4 + w;
    if (node >= NN) return;
    const int start = row_start[node];
    const int cnt   = counts[node];
    const float dinv = deg_inv[node];
    const int g  = lane / LPR;
    const int wo = (lane % LPR) * 4;       // word offset within row
    const uint32* ftw = (const uint32*)feats + wo;

    // load up to 64 edge indices, one per lane; inactive lanes -> zero row NN
    int clampe = cnt > 0 ? cnt - 1 : 0;
    int myidx = csr_src[start + (lane < clampe ? lane : clampe)];
    if (lane >= cnt) myidx = NN;

    float acc[8] = {};
    const int nb = cnt < 64 ? cnt : 64;
    for (int j = 0; j < nb; j += EPI) {
        uint4 x_[U];
#pragma unroll
        for (int u = 0; u < U; ++u) {
            int idx = __shfl(myidx, j + u * EPW + g);   // <= 63 always
            x_[u] = *(const uint4*)(ftw + (size_t)idx * DW);
        }
#pragma unroll
        for (int u = 0; u < U; ++u) {
            acc[0] += bf16_to_f(x_[u].x & 0xFFFFu); acc[1] += bf16_to_f(x_[u].x >> 16);
            acc[2] += bf16_to_f(x_[u].y & 0xFFFFu); acc[3] += bf16_to_f(x_[u].y >> 16);
            acc[4] += bf16_to_f(x_[u].z & 0xFFFFu); acc[5] += bf16_to_f(x_[u].z >> 16);
            acc[6] += bf16_to_f(x_[u].w & 0xFFFFu); acc[7] += bf16_to_f(x_[u].w >> 16);
        }
    }
    // rare tail: degree > 64
    for (int j = 64; j < cnt; j += EPW) {
        int e = j + g;
        int idx = (e < cnt) ? csr_src[start + e] : NN;
        uint4 x = *(const uint4*)(ftw + (size_t)idx * DW);
        acc[0] += bf16_to_f(x.x & 0xFFFFu); acc[1] += bf16_to_f(x.x >> 16);
        acc[2] += bf16_to_f(x.y & 0xFFFFu); acc[3] += bf16_to_f(x.y >> 16);
        acc[4] += bf16_to_f(x.z & 0xFFFFu); acc[5] += bf16_to_f(x.z >> 16);
        acc[6] += bf16_to_f(x.w & 0xFFFFu); acc[7] += bf16_to_f(x.w >> 16);
    }
#pragma unroll
    for (int k = 0; k < 8; ++k) {
        if (LPR <= 16) acc[k] += __shfl_xor(acc[k], 16);
        acc[k] += __shfl_xor(acc[k], 32);
    }
    if (g == 0) {
        uint4 o;
        o.x = f_to_bf16(acc[0] * dinv) | (f_to_bf16(acc[1] * dinv) << 16);
        o.y = f_to_bf16(acc[2] * dinv) | (f_to_bf16(acc[3] * dinv) << 16);
        o.z = f_to_bf16(acc[4] * dinv) | (f_to_bf16(acc[5] * dinv) << 16);
        o.w = f_to_bf16(acc[6] * dinv) | (f_to_bf16(acc[7] * dinv) << 16);
        *(uint4*)((uint32*)outp + (size_t)node * DW + wo) = o;
    }
}

// ---------------- fused GEMM: C = A1*B1 + A2*B2 + bias (+relu->bf16) ----------------
// A1,A2: [M_PAD][K1] bf16 row-major. BT: [256][2*K1] bf16 (transposed, stacked).
// 64 x 256 tile (full N per block -> A staged ONCE; B L2-resident). 782 blocks.
// BK=64, 4 waves side-by-side in N. LDS XOR-swizzled (rule #21 on the source).
template<int RELU_BF16>
__global__ __launch_bounds__(256)
void gemm_kernel(const u16* __restrict__ A1, const u16* __restrict__ A2, int K1,
                 const u16* __restrict__ BT, const float* __restrict__ bias,
                 void* __restrict__ outp, int M) {
    __shared__ char lds[40960];   // A: [0,8192), B: [8192,40960)
    const int tid = threadIdx.x;
    const int w = tid >> 6, lane = tid & 63;
    const int brow = blockIdx.x * 64;
    const int Ktot = 2 * K1;
    const int NT = Ktot >> 6;   // K-tiles of 64
    const int T1 = K1 >> 6;     // tiles from A1
    const int l15 = lane & 15, l7 = lane & 7, kg = lane >> 4;
    const int srow = w * 8 + (lane >> 3);   // staging row within 32-row issue group
    const int scb = (lane & 7) * 16;        // staging byte-col slot
    const size_t sA = (size_t)K1 * 2;       // bytes per A row
    const size_t sB = (size_t)Ktot * 2;     // bytes per BT row

    floatx4 acc[4][4] = {};

    for (int kt = 0; kt < NT; ++kt) {
        const char* Ab; int ka;
        if (kt < T1) { Ab = (const char*)A1; ka = kt * 64; }
        else         { Ab = (const char*)A2; ka = (kt - T1) * 64; }
#pragma unroll
        for (int i = 0; i < 2; ++i) {       // A: 64 rows
            int row = i * 32 + srow;
            const char* g = Ab + (size_t)(brow + row) * sA + ka * 2 + (scb ^ ((row & 7) << 4));
            gload_lds16(g, &lds[i * 4096 + w * 1024]);
        }
#pragma unroll
        for (int i = 0; i < 8; ++i) {       // B: all 256 BT rows
            int row = i * 32 + srow;
            const char* g = (const char*)BT + (size_t)row * sB + kt * 128 + (scb ^ ((row & 7) << 4));
            gload_lds16(g, &lds[8192 + i * 4096 + w * 1024]);
        }
        __syncthreads();
#pragma unroll
        for (int kk = 0; kk < 2; ++kk) {
            short8 a[4], b[4];
            const int cbyte = (kk * 64 + kg * 16) ^ (l7 << 4);
#pragma unroll
            for (int m = 0; m < 4; ++m)
                a[m] = *(const short8*)&lds[(m * 16 + l15) * 128 + cbyte];
#pragma unroll
            for (int n = 0; n < 4; ++n)
                b[n] = *(const short8*)&lds[8192 + (w * 64 + n * 16 + l15) * 128 + cbyte];
#pragma unroll
            for (int m = 0; m < 4; ++m)
#pragma unroll
                for (int n = 0; n < 4; ++n)
                    acc[m][n] = __builtin_amdgcn_mfma_f32_16x16x32_bf16(a[m], b[n], acc[m][n], 0, 0, 0);
        }
        __syncthreads();
    }

    const int ocol0 = w * 64;
#pragma unroll
    for (int m = 0; m < 4; ++m) {
#pragma unroll
        for (int j = 0; j < 4; ++j) {
            int row = brow + m * 16 + kg * 4 + j;
            if (row < M) {
#pragma unroll
                for (int n = 0; n < 4; ++n) {
                    int col = ocol0 + n * 16 + l15;
                    float v = acc[m][n][j] + bias[col];
                    if (RELU_BF16) {
                        v = fmaxf(v, 0.0f);
                        ((u16*)outp)[(size_t)row * H_F + col] = (u16)f_to_bf16(v);
                    } else {
                        ((float*)outp)[(size_t)row * H_F + col] = v;
                    }
                }
            }
        }
    }
}

// ---------------- launch ----------------

extern "C" void kernel_launch(void* const* d_in, const int* in_sizes, int n_in,
                              void* d_out, int out_size, void* d_ws, size_t ws_size,
                              hipStream_t stream) {
    const float* in_feat  = (const float*)d_in[0];
    const int*   src      = (const int*)d_in[1];
    const int*   dst      = (const int*)d_in[2];
    const float* W_self1  = (const float*)d_in[3];
    const float* W_neigh1 = (const float*)d_in[4];
    const float* b1       = (const float*)d_in[5];
    const float* W_self2  = (const float*)d_in[6];
    const float* W_neigh2 = (const float*)d_in[7];
    const float* b2       = (const float*)d_in[8];
    float* out = (float*)d_out;

    char* p = (char*)d_ws;
    auto alloc = [&](size_t bytes) { char* r = p; p += (bytes + 255) & ~(size_t)255; return r; };
    int*   counts4    = (int*)alloc((size_t)4 * NN * 4);
    int*   base4      = (int*)alloc((size_t)4 * NN * 4);
    int*   counts_tot = (int*)alloc((size_t)NN * 4);
    int*   row_start  = (int*)alloc((size_t)NN * 4);
    int*   partials   = (int*)alloc(256 * 4);
    float* deg_inv    = (float*)alloc((size_t)NN * 4);
    int*   rank       = (int*)alloc((size_t)NE * 4);
    int*   csr_src    = (int*)alloc((size_t)NE * 4 + 256);
    u16*   inA        = (u16*)alloc((size_t)M_PAD * IN_F * 2);
    u16*   hn1        = (u16*)alloc((size_t)M_PAD * IN_F * 2);
    u16*   h          = (u16*)alloc((size_t)M_PAD * H_F * 2);
    u16*   hn2        = (u16*)alloc((size_t)M_PAD * H_F * 2);
    u16*   BT1        = (u16*)alloc((size_t)256 * 256 * 2);
    u16*   BT2        = (u16*)alloc((size_t)256 * 512 * 2);

    hipMemsetAsync(counts4, 0, (size_t)4 * NN * 4, stream);

    prep_kernel<<<(PREP_TOTAL + 255) / 256, 256, 0, stream>>>(
        in_feat, inA, W_self1, W_neigh1, BT1, W_self2, W_neigh2, BT2, h, dst, counts4, rank);

    const int SB = (NN + 255) / 256;   // 196
    scan1_kernel<<<SB, 256, 0, stream>>>(counts4, row_start, partials, NN);
    scan3_kernel<<<SB, 256, 0, stream>>>(row_start, partials, counts4, base4, counts_tot,
                                         deg_inv, NN, SB);
    scatter_kernel<<<(NE + 255) / 256, 256, 0, stream>>>(src, dst, rank, base4, csr_src);

    // layer 1
    agg_kernel<IN_F / 2><<<(NN + 3) / 4, 256, 0, stream>>>(inA, csr_src, row_start, counts_tot, deg_inv, hn1);
    gemm_kernel<1><<<M_PAD / 64, 256, 0, stream>>>(inA, hn1, 128, BT1, b1, (void*)h, NN);
    // layer 2
    agg_kernel<H_F / 2><<<(NN + 3) / 4, 256, 0, stream>>>(h, csr_src, row_start, counts_tot, deg_inv, hn2);
    gemm_kernel<0><<<M_PAD / 64, 256, 0, stream>>>(h, hn2, 256, BT2, b2, (void*)out, NN);
}